// Round 24
// baseline (134.736 us; speedup 1.0000x reference)
//
#include <hip/hip_runtime.h>
#include <hip/hip_bf16.h>

#define T_SEQ 2048
#define DMODEL 1024
#define NHEAD 16
#define DKH 64
#define BATCH 2

typedef __attribute__((ext_vector_type(8))) short bf16x8;
typedef __attribute__((ext_vector_type(4))) float f32x4;

__device__ inline unsigned short f2bf(float f) {
  unsigned u = __builtin_bit_cast(unsigned, f);
  u += 0x7fffu + ((u >> 16) & 1u);
  return (unsigned short)(u >> 16);
}

#if __has_builtin(__builtin_amdgcn_exp2f)
__device__ inline float fast_exp2(float x) { return __builtin_amdgcn_exp2f(x); }
#else
__device__ inline float fast_exp2(float x) { return exp2f(x); }
#endif

// Packed f32x2 -> bf16x2 (RNE) via the compiler's cvt_pk path (builtin,
// hazard-safe). memcpy not bit_cast: __hip_bfloat162 isn't trivially copyable.
__device__ inline unsigned pack2bf(float a, float b) {
  __hip_bfloat162 t = __float22bfloat162_rn(float2{a, b});
  unsigned r;
  __builtin_memcpy(&r, &t, 4);
  return r;
}

// Merged cast: xb[4096][1024] bf16 = x; Wqkv[3072][1024] bf16 =
// (wq*qscale | wk | wv); Wob[1024][1024] bf16 = wo. One launch.
__global__ void castall(const float* __restrict__ x,
                        const float* __restrict__ wq, const float* __restrict__ wk,
                        const float* __restrict__ wv, const float* __restrict__ wo,
                        unsigned short* __restrict__ xb,
                        unsigned short* __restrict__ Wqkv, unsigned short* __restrict__ Wob,
                        float qscale) {
  const int NX = BATCH * T_SEQ * DMODEL;   // 4,194,304
  const int NW = DMODEL * DMODEL;          // 1,048,576
  int i = (blockIdx.x * blockDim.x + threadIdx.x) * 4;
  if (i < NX) {
    float4 v = *reinterpret_cast<const float4*>(x + i);
    ushort4 o;
    o.x = f2bf(v.x); o.y = f2bf(v.y); o.z = f2bf(v.z); o.w = f2bf(v.w);
    *reinterpret_cast<ushort4*>(xb + i) = o;
    return;
  }
  int j = i - NX;
  if (j >= 4 * NW) return;
  if (j < 3 * NW) {
    const float* src; float sc = 1.0f; int off = j;
    if (j < NW) { src = wq; sc = qscale; }
    else if (j < 2 * NW) { src = wk; off = j - NW; }
    else { src = wv; off = j - 2 * NW; }
    float4 v = *reinterpret_cast<const float4*>(src + off);
    ushort4 o;
    o.x = f2bf(v.x * sc); o.y = f2bf(v.y * sc); o.z = f2bf(v.z * sc); o.w = f2bf(v.w * sc);
    *reinterpret_cast<ushort4*>(Wqkv + j) = o;
  } else {
    int off = j - 3 * NW;
    float4 v = *reinterpret_cast<const float4*>(wo + off);
    ushort4 o;
    o.x = f2bf(v.x); o.y = f2bf(v.y); o.z = f2bf(v.z); o.w = f2bf(v.w);
    *reinterpret_cast<ushort4*>(Wob + off) = o;
  }
}

// Fused QKV projection GEMM, BM=64 x BN=128 tile (proven).
// Section (bn>>10, block-uniform): 0 -> Q [B,H,T,DK] (bias bq*qscale),
// 1 -> K [B,H,T,DK], 2 -> V^T [B,H,DK,T].
__global__ __launch_bounds__(256) void gemm_qkv(
    const unsigned short* __restrict__ A,
    const unsigned short* __restrict__ Bw,
    const float* __restrict__ bq,
    const float* __restrict__ bk,
    const float* __restrict__ bv,
    unsigned short* __restrict__ Qb,
    unsigned short* __restrict__ Kb,
    unsigned short* __restrict__ Vtb,
    int K, float qscale)
{
  __shared__ __attribute__((aligned(16))) unsigned short As[64][72];
  __shared__ __attribute__((aligned(16))) unsigned short Bs[128][72];
  const int tid = threadIdx.x;
  const int lane = tid & 63, wid = tid >> 6;
  const int wm = (wid >> 1) * 32, wn = (wid & 1) * 64;
  const int lr = lane & 15, lk = (lane >> 4) * 8, lg = lane >> 4;
  const int bm = blockIdx.y * 64, bn = blockIdx.x * 128;
  const int srow = tid >> 3, scol = (tid & 7) * 8;

  f32x4 acc[2][4] = {};
  for (int k0 = 0; k0 < K; k0 += 64) {
    uint4 a0 = *reinterpret_cast<const uint4*>(&A[(size_t)(bm + srow) * K + k0 + scol]);
    uint4 a1 = *reinterpret_cast<const uint4*>(&A[(size_t)(bm + srow + 32) * K + k0 + scol]);
    uint4 b0 = *reinterpret_cast<const uint4*>(&Bw[(size_t)(bn + srow) * K + k0 + scol]);
    uint4 b1 = *reinterpret_cast<const uint4*>(&Bw[(size_t)(bn + srow + 32) * K + k0 + scol]);
    uint4 b2 = *reinterpret_cast<const uint4*>(&Bw[(size_t)(bn + srow + 64) * K + k0 + scol]);
    uint4 b3 = *reinterpret_cast<const uint4*>(&Bw[(size_t)(bn + srow + 96) * K + k0 + scol]);
    *reinterpret_cast<uint4*>(&As[srow][scol]) = a0;
    *reinterpret_cast<uint4*>(&As[srow + 32][scol]) = a1;
    *reinterpret_cast<uint4*>(&Bs[srow][scol]) = b0;
    *reinterpret_cast<uint4*>(&Bs[srow + 32][scol]) = b1;
    *reinterpret_cast<uint4*>(&Bs[srow + 64][scol]) = b2;
    *reinterpret_cast<uint4*>(&Bs[srow + 96][scol]) = b3;
    __syncthreads();
#pragma unroll
    for (int kc = 0; kc < 64; kc += 32) {
      bf16x8 fa[2], fb[4];
#pragma unroll
      for (int i = 0; i < 2; ++i)
        fa[i] = *reinterpret_cast<const bf16x8*>(&As[wm + i * 16 + lr][kc + lk]);
#pragma unroll
      for (int j = 0; j < 4; ++j)
        fb[j] = *reinterpret_cast<const bf16x8*>(&Bs[wn + j * 16 + lr][kc + lk]);
#pragma unroll
      for (int i = 0; i < 2; ++i)
#pragma unroll
        for (int j = 0; j < 4; ++j)
          acc[i][j] = __builtin_amdgcn_mfma_f32_16x16x32_bf16(fa[i], fb[j], acc[i][j], 0, 0, 0);
    }
    __syncthreads();
  }

  const int sec = bn >> 10;   // block-uniform: 0=Q, 1=K, 2=V
#pragma unroll
  for (int i = 0; i < 2; ++i)
#pragma unroll
    for (int j = 0; j < 4; ++j) {
      const int nbase = bn + wn + j * 16 + lr;
      const int d = nbase & (DMODEL - 1), hh = d >> 6, dk = d & 63;
      const float bval = (sec == 0) ? bq[d] * qscale : ((sec == 1) ? bk[d] : bv[d]);
      if (sec == 2) {
        const int m0 = bm + wm + i * 16 + lg * 4;
        const int bb = m0 >> 11, tp = m0 & (T_SEQ - 1);
        ushort4 o;
        o.x = f2bf(acc[i][j][0] + bval);
        o.y = f2bf(acc[i][j][1] + bval);
        o.z = f2bf(acc[i][j][2] + bval);
        o.w = f2bf(acc[i][j][3] + bval);
        *reinterpret_cast<ushort4*>(
            &Vtb[(size_t)((bb * NHEAD + hh) * DKH + dk) * T_SEQ + tp]) = o;
      } else {
        unsigned short* dst = (sec == 0) ? Qb : Kb;
#pragma unroll
        for (int t = 0; t < 4; ++t) {
          const int m = bm + wm + i * 16 + lg * 4 + t;
          const int bb = m >> 11, tp = m & (T_SEQ - 1);
          dst[(size_t)((bb * NHEAD + hh) * T_SEQ + tp) * DKH + dk] = f2bf(acc[i][j][t] + bval);
        }
      }
    }
}

// Output projection GEMM: C = A @ Wob^T + bo, fp32 out, BM=64 x BN=128 tile.
__global__ __launch_bounds__(256) void gemm_out(
    const unsigned short* __restrict__ A,
    const unsigned short* __restrict__ Bw,
    const float* __restrict__ bias,
    float* __restrict__ outp,
    int N, int K)
{
  __shared__ __attribute__((aligned(16))) unsigned short As[64][72];
  __shared__ __attribute__((aligned(16))) unsigned short Bs[128][72];
  const int tid = threadIdx.x;
  const int lane = tid & 63, wid = tid >> 6;
  const int wm = (wid >> 1) * 32, wn = (wid & 1) * 64;
  const int lr = lane & 15, lk = (lane >> 4) * 8, lg = lane >> 4;
  const int bm = blockIdx.y * 64, bn = blockIdx.x * 128;
  const int srow = tid >> 3, scol = (tid & 7) * 8;

  f32x4 acc[2][4] = {};
  for (int k0 = 0; k0 < K; k0 += 64) {
    uint4 a0 = *reinterpret_cast<const uint4*>(&A[(size_t)(bm + srow) * K + k0 + scol]);
    uint4 a1 = *reinterpret_cast<const uint4*>(&A[(size_t)(bm + srow + 32) * K + k0 + scol]);
    uint4 b0 = *reinterpret_cast<const uint4*>(&Bw[(size_t)(bn + srow) * K + k0 + scol]);
    uint4 b1 = *reinterpret_cast<const uint4*>(&Bw[(size_t)(bn + srow + 32) * K + k0 + scol]);
    uint4 b2 = *reinterpret_cast<const uint4*>(&Bw[(size_t)(bn + srow + 64) * K + k0 + scol]);
    uint4 b3 = *reinterpret_cast<const uint4*>(&Bw[(size_t)(bn + srow + 96) * K + k0 + scol]);
    *reinterpret_cast<uint4*>(&As[srow][scol]) = a0;
    *reinterpret_cast<uint4*>(&As[srow + 32][scol]) = a1;
    *reinterpret_cast<uint4*>(&Bs[srow][scol]) = b0;
    *reinterpret_cast<uint4*>(&Bs[srow + 32][scol]) = b1;
    *reinterpret_cast<uint4*>(&Bs[srow + 64][scol]) = b2;
    *reinterpret_cast<uint4*>(&Bs[srow + 96][scol]) = b3;
    __syncthreads();
#pragma unroll
    for (int kc = 0; kc < 64; kc += 32) {
      bf16x8 fa[2], fb[4];
#pragma unroll
      for (int i = 0; i < 2; ++i)
        fa[i] = *reinterpret_cast<const bf16x8*>(&As[wm + i * 16 + lr][kc + lk]);
#pragma unroll
      for (int j = 0; j < 4; ++j)
        fb[j] = *reinterpret_cast<const bf16x8*>(&Bs[wn + j * 16 + lr][kc + lk]);
#pragma unroll
      for (int i = 0; i < 2; ++i)
#pragma unroll
        for (int j = 0; j < 4; ++j)
          acc[i][j] = __builtin_amdgcn_mfma_f32_16x16x32_bf16(fa[i], fb[j], acc[i][j], 0, 0, 0);
    }
    __syncthreads();
  }

#pragma unroll
  for (int i = 0; i < 2; ++i)
#pragma unroll
    for (int j = 0; j < 4; ++j) {
      const int nbase = bn + wn + j * 16 + lr;
      const float bval = bias[nbase];
#pragma unroll
      for (int t = 0; t < 4; ++t) {
        const int m = bm + wm + i * 16 + lg * 4 + t;
        outp[(size_t)m * N + nbase] = acc[i][j][t] + bval;
      }
    }
}

// Flash attention — round-19 loop body VERBATIM + wave-0-combines epilogue:
// waves 1..3 publish O/l partials to LDS (3 slabs, 52 KB -> 3 blocks/CU,
// +50% resident waves vs 70 KB/2 blocks); wave 0 keeps its partial in
// registers, sums after one barrier, and writes Y in its own fragment
// layout (the round-5-validated 8B epilogue).
__global__ __launch_bounds__(256, 2) void attn_k(
    const unsigned short* __restrict__ Q,
    const unsigned short* __restrict__ K,
    const unsigned short* __restrict__ Vt,
    unsigned short* __restrict__ Yb)
{
  __shared__ __attribute__((aligned(16))) float Ol[3][64][68];
  __shared__ float Lp[4][64];
  const int tid = threadIdx.x;
  const int lane = tid & 63, w = tid >> 6;
  const int lr = lane & 15, g = lane >> 4;
  const int bid = blockIdx.x;
  const int swz = ((bid & 7) << 7) | (bid >> 3);
  const int bh = swz >> 5;
  const int bq = (T_SEQ / 64 - 1) - (swz & 31);   // longest-first per chunk
  const int b = bh >> 4, h = bh & 15;
  const int q0 = bq * 64;
  const int nt = bq + 1, last = nt - 1;

  const unsigned short* Qb = Q + (size_t)bh * T_SEQ * DKH;
  const unsigned short* Kb = K + (size_t)bh * T_SEQ * DKH;
  const unsigned short* Vb = Vt + (size_t)bh * DKH * T_SEQ;

  bf16x8 qa[4][2];
#pragma unroll
  for (int qf4 = 0; qf4 < 4; ++qf4)
#pragma unroll
    for (int kk = 0; kk < 2; ++kk)
      qa[qf4][kk] = *reinterpret_cast<const bf16x8*>(
          &Qb[(size_t)(q0 + qf4 * 16 + lr) * DKH + kk * 32 + g * 8]);

  f32x4 o[4][4] = {};
  float lsum[4] = {0.f, 0.f, 0.f, 0.f};

  auto tile = [&](int k0, bool masked) {
    bf16x8 ka[4][2];
#pragma unroll
    for (int f = 0; f < 4; ++f)
#pragma unroll
      for (int kk = 0; kk < 2; ++kk)
        ka[f][kk] = *reinterpret_cast<const bf16x8*>(
            &Kb[(size_t)(k0 + f * 16 + lr) * DKH + kk * 32 + g * 8]);

    bf16x8 vf[4][2];
#pragma unroll
    for (int df = 0; df < 4; ++df)
#pragma unroll
      for (int kk = 0; kk < 2; ++kk)
        vf[df][kk] = *reinterpret_cast<const bf16x8*>(
            &Vb[(size_t)(df * 16 + lr) * T_SEQ + k0 + kk * 32 + g * 8]);

    // Two q-frag pairs; each pair is the validated round-14 tile body.
#pragma unroll
    for (int qp = 0; qp < 2; ++qp) {
      // QK^T (swapped): s[qf][f] covers keys k0+f*16+4g+r, query (2qp+qf)*16+lr
      f32x4 s[2][4] = {};
#pragma unroll
      for (int f = 0; f < 4; ++f) {
        s[0][f] = __builtin_amdgcn_mfma_f32_16x16x32_bf16(ka[f][0], qa[2 * qp][0], s[0][f], 0, 0, 0);
        s[0][f] = __builtin_amdgcn_mfma_f32_16x16x32_bf16(ka[f][1], qa[2 * qp][1], s[0][f], 0, 0, 0);
        s[1][f] = __builtin_amdgcn_mfma_f32_16x16x32_bf16(ka[f][0], qa[2 * qp + 1][0], s[1][f], 0, 0, 0);
        s[1][f] = __builtin_amdgcn_mfma_f32_16x16x32_bf16(ka[f][1], qa[2 * qp + 1][1], s[1][f], 0, 0, 0);
      }

      // softmax (exp2, no max-tracking) + l partial + cvt_pk pack
      unsigned pk[2][4][2];
#pragma unroll
      for (int qf = 0; qf < 2; ++qf)
#pragma unroll
        for (int f = 0; f < 4; ++f) {
          float p[4];
#pragma unroll
          for (int r = 0; r < 4; ++r) {
            float sv = s[qf][f][r];
            if (masked)
              sv = (k0 + f * 16 + g * 4 + r <= q0 + (2 * qp + qf) * 16 + lr) ? sv : -1e30f;
            p[r] = fast_exp2(sv);
          }
          lsum[2 * qp + qf] += (p[0] + p[1]) + (p[2] + p[3]);
          pk[qf][f][0] = pack2bf(p[0], p[1]);
          pk[qf][f][1] = pack2bf(p[2], p[3]);
        }

      // Redistribute C/D layout -> B-frag layout via shuffles (proven).
      const int sA = lr + 16 * (2 * (g & 1));
      const int sB = sA + 16;
#pragma unroll
      for (int qf = 0; qf < 2; ++qf)
#pragma unroll
        for (int kk = 0; kk < 2; ++kk) {
          int dw[4];
#pragma unroll
          for (int j2 = 0; j2 < 4; ++j2) {
            const int S = (j2 < 2) ? sA : sB;
            int v0 = __shfl((int)pk[qf][2 * kk][j2 & 1], S, 64);
            int v1 = __shfl((int)pk[qf][2 * kk + 1][j2 & 1], S, 64);
            dw[j2] = (g & 2) ? v1 : v0;
          }
          int4 dwi = make_int4(dw[0], dw[1], dw[2], dw[3]);
          bf16x8 pa = __builtin_bit_cast(bf16x8, dwi);
#pragma unroll
          for (int df = 0; df < 4; ++df)
            o[2 * qp + qf][df] = __builtin_amdgcn_mfma_f32_16x16x32_bf16(
                vf[df][kk], pa, o[2 * qp + qf][df], 0, 0, 0);
        }
    }
  };

  for (int t = w; t < last; t += 4) tile(t * 64, false);
  if (last >= 0 && (last & 3) == w) tile(last * 64, true);

  // l partial: reduce across the 4 g-groups (q = lr in every group)
#pragma unroll
  for (int qf4 = 0; qf4 < 4; ++qf4) {
    lsum[qf4] += __shfl_xor(lsum[qf4], 16);
    lsum[qf4] += __shfl_xor(lsum[qf4], 32);
  }

  // Waves 1..3 publish partials to LDS; wave 0 keeps its own in registers.
  if (w != 0) {
#pragma unroll
    for (int qf4 = 0; qf4 < 4; ++qf4) {
      if (g == 0) Lp[w][qf4 * 16 + lr] = lsum[qf4];
#pragma unroll
      for (int df = 0; df < 4; ++df)
        *reinterpret_cast<f32x4*>(&Ol[w - 1][qf4 * 16 + lr][df * 16 + g * 4]) = o[qf4][df];
    }
  }
  __syncthreads();

  // Wave 0 combines and writes Y (lane (lr,g): q = q0+qf4*16+lr,
  // d = df*16+g*4 .. +3 — the round-5-validated fragment epilogue).
  if (w == 0) {
#pragma unroll
    for (int qf4 = 0; qf4 < 4; ++qf4) {
      const int q = qf4 * 16 + lr;
      const float l = lsum[qf4] + Lp[1][q] + Lp[2][q] + Lp[3][q];
      const float rl = 1.0f / l;
#pragma unroll
      for (int df = 0; df < 4; ++df) {
        f32x4 s4 = o[qf4][df];
#pragma unroll
        for (int wp = 0; wp < 3; ++wp) {
          f32x4 a = *reinterpret_cast<const f32x4*>(&Ol[wp][q][df * 16 + g * 4]);
          s4[0] += a[0]; s4[1] += a[1]; s4[2] += a[2]; s4[3] += a[3];
        }
        uint2 ov;
        ov.x = pack2bf(s4[0] * rl, s4[1] * rl);
        ov.y = pack2bf(s4[2] * rl, s4[3] * rl);
        *reinterpret_cast<uint2*>(
            &Yb[(size_t)(b * T_SEQ + q0 + q) * DMODEL + h * DKH + df * 16 + g * 4]) = ov;
      }
    }
  }
}

extern "C" void kernel_launch(void* const* d_in, const int* in_sizes, int n_in,
                              void* d_out, int out_size, void* d_ws, size_t ws_size,
                              hipStream_t stream) {
  const float* x  = (const float*)d_in[0];
  const float* wq = (const float*)d_in[1];
  const float* bq = (const float*)d_in[2];
  const float* wk = (const float*)d_in[3];
  const float* bk = (const float*)d_in[4];
  const float* wv = (const float*)d_in[5];
  const float* bv = (const float*)d_in[6];
  const float* wo = (const float*)d_in[7];
  const float* bo = (const float*)d_in[8];

  char* ws = (char*)d_ws;
  unsigned short* xb   = (unsigned short*)(ws + (size_t)0);          // [0,8) MB
  unsigned short* Wqkv = (unsigned short*)(ws + ((size_t)8  << 20)); // [8,14) MB
  unsigned short* Wob  = (unsigned short*)(ws + ((size_t)14 << 20)); // [14,16) MB
  unsigned short* Qb   = (unsigned short*)(ws + ((size_t)16 << 20)); // [16,24) MB
  unsigned short* Kb   = (unsigned short*)(ws + ((size_t)24 << 20)); // [24,32) MB
  unsigned short* Vtb  = (unsigned short*)(ws + ((size_t)32 << 20)); // [32,40) MB
  unsigned short* Yb   = (unsigned short*)(ws + ((size_t)40 << 20)); // [40,48) MB

  const int M = BATCH * T_SEQ;      // 4096
  const int N = DMODEL;             // 1024
  const int Kd = DMODEL;            // 1024
  const float qscale = 0.125f * 1.44269504f;  // 1/sqrt(dk) * log2(e)

  const int ncast = (M * DMODEL + 4 * DMODEL * DMODEL) / 4;  // elements/4
  castall<<<(ncast + 255) / 256, 256, 0, stream>>>(
      x, wq, wk, wv, wo, xb, Wqkv, Wob, qscale);

  gemm_qkv<<<dim3(3 * N / 128, M / 64), 256, 0, stream>>>(
      xb, Wqkv, bq, bk, bv, Qb, Kb, Vtb, Kd, qscale);

  attn_k<<<dim3((T_SEQ / 64) * BATCH * NHEAD), 256, 0, stream>>>(Qb, Kb, Vtb, Yb);

  gemm_out<<<dim3(N / 128, M / 64), 256, 0, stream>>>(Yb, Wob, bo, (float*)d_out, N, Kd);
}

// Round 25
// 131.815 us; speedup vs baseline: 1.0222x; 1.0222x over previous
//
#include <hip/hip_runtime.h>
#include <hip/hip_bf16.h>

#define T_SEQ 2048
#define DMODEL 1024
#define NHEAD 16
#define DKH 64
#define BATCH 2

typedef __attribute__((ext_vector_type(8))) short bf16x8;
typedef __attribute__((ext_vector_type(4))) float f32x4;

__device__ inline unsigned short f2bf(float f) {
  unsigned u = __builtin_bit_cast(unsigned, f);
  u += 0x7fffu + ((u >> 16) & 1u);
  return (unsigned short)(u >> 16);
}

#if __has_builtin(__builtin_amdgcn_exp2f)
__device__ inline float fast_exp2(float x) { return __builtin_amdgcn_exp2f(x); }
#else
__device__ inline float fast_exp2(float x) { return exp2f(x); }
#endif

// Packed f32x2 -> bf16x2 (RNE) via the compiler's cvt_pk path (builtin,
// hazard-safe). memcpy not bit_cast: __hip_bfloat162 isn't trivially copyable.
__device__ inline unsigned pack2bf(float a, float b) {
  __hip_bfloat162 t = __float22bfloat162_rn(float2{a, b});
  unsigned r;
  __builtin_memcpy(&r, &t, 4);
  return r;
}

// Merged cast: xb[4096][1024] bf16 = x; Wqkv[3072][1024] bf16 =
// (wq*qscale | wk | wv); Wob[1024][1024] bf16 = wo. One launch.
__global__ void castall(const float* __restrict__ x,
                        const float* __restrict__ wq, const float* __restrict__ wk,
                        const float* __restrict__ wv, const float* __restrict__ wo,
                        unsigned short* __restrict__ xb,
                        unsigned short* __restrict__ Wqkv, unsigned short* __restrict__ Wob,
                        float qscale) {
  const int NX = BATCH * T_SEQ * DMODEL;   // 4,194,304
  const int NW = DMODEL * DMODEL;          // 1,048,576
  int i = (blockIdx.x * blockDim.x + threadIdx.x) * 4;
  if (i < NX) {
    float4 v = *reinterpret_cast<const float4*>(x + i);
    ushort4 o;
    o.x = f2bf(v.x); o.y = f2bf(v.y); o.z = f2bf(v.z); o.w = f2bf(v.w);
    *reinterpret_cast<ushort4*>(xb + i) = o;
    return;
  }
  int j = i - NX;
  if (j >= 4 * NW) return;
  if (j < 3 * NW) {
    const float* src; float sc = 1.0f; int off = j;
    if (j < NW) { src = wq; sc = qscale; }
    else if (j < 2 * NW) { src = wk; off = j - NW; }
    else { src = wv; off = j - 2 * NW; }
    float4 v = *reinterpret_cast<const float4*>(src + off);
    ushort4 o;
    o.x = f2bf(v.x * sc); o.y = f2bf(v.y * sc); o.z = f2bf(v.z * sc); o.w = f2bf(v.w * sc);
    *reinterpret_cast<ushort4*>(Wqkv + j) = o;
  } else {
    int off = j - 3 * NW;
    float4 v = *reinterpret_cast<const float4*>(wo + off);
    ushort4 o;
    o.x = f2bf(v.x); o.y = f2bf(v.y); o.z = f2bf(v.z); o.w = f2bf(v.w);
    *reinterpret_cast<ushort4*>(Wob + off) = o;
  }
}

// Fused QKV projection GEMM, BM=64 x BN=128 tile (16 MFMAs/K-step/wave,
// barriers amortized 2x vs 64^2; LDS 27 KB keeps 5 blocks/CU).
// Section (bn>>10, block-uniform; 1024%128==0): 0 -> Q [B,H,T,DK]
// (bias bq*qscale), 1 -> K [B,H,T,DK], 2 -> V^T [B,H,DK,T].
__global__ __launch_bounds__(256) void gemm_qkv(
    const unsigned short* __restrict__ A,
    const unsigned short* __restrict__ Bw,
    const float* __restrict__ bq,
    const float* __restrict__ bk,
    const float* __restrict__ bv,
    unsigned short* __restrict__ Qb,
    unsigned short* __restrict__ Kb,
    unsigned short* __restrict__ Vtb,
    int K, float qscale)
{
  __shared__ __attribute__((aligned(16))) unsigned short As[64][72];
  __shared__ __attribute__((aligned(16))) unsigned short Bs[128][72];
  const int tid = threadIdx.x;
  const int lane = tid & 63, wid = tid >> 6;
  const int wm = (wid >> 1) * 32, wn = (wid & 1) * 64;
  const int lr = lane & 15, lk = (lane >> 4) * 8, lg = lane >> 4;
  const int bm = blockIdx.y * 64, bn = blockIdx.x * 128;
  const int srow = tid >> 3, scol = (tid & 7) * 8;

  f32x4 acc[2][4] = {};
  for (int k0 = 0; k0 < K; k0 += 64) {
    uint4 a0 = *reinterpret_cast<const uint4*>(&A[(size_t)(bm + srow) * K + k0 + scol]);
    uint4 a1 = *reinterpret_cast<const uint4*>(&A[(size_t)(bm + srow + 32) * K + k0 + scol]);
    uint4 b0 = *reinterpret_cast<const uint4*>(&Bw[(size_t)(bn + srow) * K + k0 + scol]);
    uint4 b1 = *reinterpret_cast<const uint4*>(&Bw[(size_t)(bn + srow + 32) * K + k0 + scol]);
    uint4 b2 = *reinterpret_cast<const uint4*>(&Bw[(size_t)(bn + srow + 64) * K + k0 + scol]);
    uint4 b3 = *reinterpret_cast<const uint4*>(&Bw[(size_t)(bn + srow + 96) * K + k0 + scol]);
    *reinterpret_cast<uint4*>(&As[srow][scol]) = a0;
    *reinterpret_cast<uint4*>(&As[srow + 32][scol]) = a1;
    *reinterpret_cast<uint4*>(&Bs[srow][scol]) = b0;
    *reinterpret_cast<uint4*>(&Bs[srow + 32][scol]) = b1;
    *reinterpret_cast<uint4*>(&Bs[srow + 64][scol]) = b2;
    *reinterpret_cast<uint4*>(&Bs[srow + 96][scol]) = b3;
    __syncthreads();
#pragma unroll
    for (int kc = 0; kc < 64; kc += 32) {
      bf16x8 fa[2], fb[4];
#pragma unroll
      for (int i = 0; i < 2; ++i)
        fa[i] = *reinterpret_cast<const bf16x8*>(&As[wm + i * 16 + lr][kc + lk]);
#pragma unroll
      for (int j = 0; j < 4; ++j)
        fb[j] = *reinterpret_cast<const bf16x8*>(&Bs[wn + j * 16 + lr][kc + lk]);
#pragma unroll
      for (int i = 0; i < 2; ++i)
#pragma unroll
        for (int j = 0; j < 4; ++j)
          acc[i][j] = __builtin_amdgcn_mfma_f32_16x16x32_bf16(fa[i], fb[j], acc[i][j], 0, 0, 0);
    }
    __syncthreads();
  }

  const int sec = bn >> 10;   // block-uniform: 0=Q, 1=K, 2=V
#pragma unroll
  for (int i = 0; i < 2; ++i)
#pragma unroll
    for (int j = 0; j < 4; ++j) {
      const int nbase = bn + wn + j * 16 + lr;
      const int d = nbase & (DMODEL - 1), hh = d >> 6, dk = d & 63;
      const float bval = (sec == 0) ? bq[d] * qscale : ((sec == 1) ? bk[d] : bv[d]);
      if (sec == 2) {
        const int m0 = bm + wm + i * 16 + lg * 4;
        const int bb = m0 >> 11, tp = m0 & (T_SEQ - 1);
        ushort4 o;
        o.x = f2bf(acc[i][j][0] + bval);
        o.y = f2bf(acc[i][j][1] + bval);
        o.z = f2bf(acc[i][j][2] + bval);
        o.w = f2bf(acc[i][j][3] + bval);
        *reinterpret_cast<ushort4*>(
            &Vtb[(size_t)((bb * NHEAD + hh) * DKH + dk) * T_SEQ + tp]) = o;
      } else {
        unsigned short* dst = (sec == 0) ? Qb : Kb;
#pragma unroll
        for (int t = 0; t < 4; ++t) {
          const int m = bm + wm + i * 16 + lg * 4 + t;
          const int bb = m >> 11, tp = m & (T_SEQ - 1);
          dst[(size_t)((bb * NHEAD + hh) * T_SEQ + tp) * DKH + dk] = f2bf(acc[i][j][t] + bval);
        }
      }
    }
}

// Output projection GEMM: C = A @ Wob^T + bo, fp32 out, BM=64 x BN=128 tile.
__global__ __launch_bounds__(256) void gemm_out(
    const unsigned short* __restrict__ A,
    const unsigned short* __restrict__ Bw,
    const float* __restrict__ bias,
    float* __restrict__ outp,
    int N, int K)
{
  __shared__ __attribute__((aligned(16))) unsigned short As[64][72];
  __shared__ __attribute__((aligned(16))) unsigned short Bs[128][72];
  const int tid = threadIdx.x;
  const int lane = tid & 63, wid = tid >> 6;
  const int wm = (wid >> 1) * 32, wn = (wid & 1) * 64;
  const int lr = lane & 15, lk = (lane >> 4) * 8, lg = lane >> 4;
  const int bm = blockIdx.y * 64, bn = blockIdx.x * 128;
  const int srow = tid >> 3, scol = (tid & 7) * 8;

  f32x4 acc[2][4] = {};
  for (int k0 = 0; k0 < K; k0 += 64) {
    uint4 a0 = *reinterpret_cast<const uint4*>(&A[(size_t)(bm + srow) * K + k0 + scol]);
    uint4 a1 = *reinterpret_cast<const uint4*>(&A[(size_t)(bm + srow + 32) * K + k0 + scol]);
    uint4 b0 = *reinterpret_cast<const uint4*>(&Bw[(size_t)(bn + srow) * K + k0 + scol]);
    uint4 b1 = *reinterpret_cast<const uint4*>(&Bw[(size_t)(bn + srow + 32) * K + k0 + scol]);
    uint4 b2 = *reinterpret_cast<const uint4*>(&Bw[(size_t)(bn + srow + 64) * K + k0 + scol]);
    uint4 b3 = *reinterpret_cast<const uint4*>(&Bw[(size_t)(bn + srow + 96) * K + k0 + scol]);
    *reinterpret_cast<uint4*>(&As[srow][scol]) = a0;
    *reinterpret_cast<uint4*>(&As[srow + 32][scol]) = a1;
    *reinterpret_cast<uint4*>(&Bs[srow][scol]) = b0;
    *reinterpret_cast<uint4*>(&Bs[srow + 32][scol]) = b1;
    *reinterpret_cast<uint4*>(&Bs[srow + 64][scol]) = b2;
    *reinterpret_cast<uint4*>(&Bs[srow + 96][scol]) = b3;
    __syncthreads();
#pragma unroll
    for (int kc = 0; kc < 64; kc += 32) {
      bf16x8 fa[2], fb[4];
#pragma unroll
      for (int i = 0; i < 2; ++i)
        fa[i] = *reinterpret_cast<const bf16x8*>(&As[wm + i * 16 + lr][kc + lk]);
#pragma unroll
      for (int j = 0; j < 4; ++j)
        fb[j] = *reinterpret_cast<const bf16x8*>(&Bs[wn + j * 16 + lr][kc + lk]);
#pragma unroll
      for (int i = 0; i < 2; ++i)
#pragma unroll
        for (int j = 0; j < 4; ++j)
          acc[i][j] = __builtin_amdgcn_mfma_f32_16x16x32_bf16(fa[i], fb[j], acc[i][j], 0, 0, 0);
    }
    __syncthreads();
  }

#pragma unroll
  for (int i = 0; i < 2; ++i)
#pragma unroll
    for (int j = 0; j < 4; ++j) {
      const int nbase = bn + wn + j * 16 + lr;
      const float bval = bias[nbase];
#pragma unroll
      for (int t = 0; t < 4; ++t) {
        const int m = bm + wm + i * 16 + lg * 4 + t;
        outp[(size_t)m * N + nbase] = acc[i][j][t] + bval;
      }
    }
}

// Flash attention — proven ~60 us: no-max softmax (scale 0.125*log2e folded
// into Q), intra-block KV-split (4 waves, t == w mod 4), 64 queries/wave,
// tile-scoped ka/vf loads, in-register shuffle P-redistribution, XCD swizzle
// (each XCD owns 4 heads x 32 q-tiles; KV set 2 MB < 4 MB XCD L2).
__global__ __launch_bounds__(256, 2) void attn_k(
    const unsigned short* __restrict__ Q,
    const unsigned short* __restrict__ K,
    const unsigned short* __restrict__ Vt,
    unsigned short* __restrict__ Yb)
{
  __shared__ float Ol[4][64][68];
  __shared__ float Lp[4][64];
  const int tid = threadIdx.x;
  const int lane = tid & 63, w = tid >> 6;
  const int lr = lane & 15, g = lane >> 4;
  const int bid = blockIdx.x;
  const int swz = ((bid & 7) << 7) | (bid >> 3);
  const int bh = swz >> 5;
  const int bq = (T_SEQ / 64 - 1) - (swz & 31);   // longest-first per chunk
  const int b = bh >> 4, h = bh & 15;
  const int q0 = bq * 64;
  const int nt = bq + 1, last = nt - 1;

  const unsigned short* Qb = Q + (size_t)bh * T_SEQ * DKH;
  const unsigned short* Kb = K + (size_t)bh * T_SEQ * DKH;
  const unsigned short* Vb = Vt + (size_t)bh * DKH * T_SEQ;

  bf16x8 qa[4][2];
#pragma unroll
  for (int qf4 = 0; qf4 < 4; ++qf4)
#pragma unroll
    for (int kk = 0; kk < 2; ++kk)
      qa[qf4][kk] = *reinterpret_cast<const bf16x8*>(
          &Qb[(size_t)(q0 + qf4 * 16 + lr) * DKH + kk * 32 + g * 8]);

  f32x4 o[4][4] = {};
  float lsum[4] = {0.f, 0.f, 0.f, 0.f};

  auto tile = [&](int k0, bool masked) {
    bf16x8 ka[4][2];
#pragma unroll
    for (int f = 0; f < 4; ++f)
#pragma unroll
      for (int kk = 0; kk < 2; ++kk)
        ka[f][kk] = *reinterpret_cast<const bf16x8*>(
            &Kb[(size_t)(k0 + f * 16 + lr) * DKH + kk * 32 + g * 8]);

    bf16x8 vf[4][2];
#pragma unroll
    for (int df = 0; df < 4; ++df)
#pragma unroll
      for (int kk = 0; kk < 2; ++kk)
        vf[df][kk] = *reinterpret_cast<const bf16x8*>(
            &Vb[(size_t)(df * 16 + lr) * T_SEQ + k0 + kk * 32 + g * 8]);

    // Two q-frag pairs; each pair is the validated round-14 tile body.
#pragma unroll
    for (int qp = 0; qp < 2; ++qp) {
      // QK^T (swapped): s[qf][f] covers keys k0+f*16+4g+r, query (2qp+qf)*16+lr
      f32x4 s[2][4] = {};
#pragma unroll
      for (int f = 0; f < 4; ++f) {
        s[0][f] = __builtin_amdgcn_mfma_f32_16x16x32_bf16(ka[f][0], qa[2 * qp][0], s[0][f], 0, 0, 0);
        s[0][f] = __builtin_amdgcn_mfma_f32_16x16x32_bf16(ka[f][1], qa[2 * qp][1], s[0][f], 0, 0, 0);
        s[1][f] = __builtin_amdgcn_mfma_f32_16x16x32_bf16(ka[f][0], qa[2 * qp + 1][0], s[1][f], 0, 0, 0);
        s[1][f] = __builtin_amdgcn_mfma_f32_16x16x32_bf16(ka[f][1], qa[2 * qp + 1][1], s[1][f], 0, 0, 0);
      }

      // softmax (exp2, no max-tracking) + l partial + cvt_pk pack
      unsigned pk[2][4][2];
#pragma unroll
      for (int qf = 0; qf < 2; ++qf)
#pragma unroll
        for (int f = 0; f < 4; ++f) {
          float p[4];
#pragma unroll
          for (int r = 0; r < 4; ++r) {
            float sv = s[qf][f][r];
            if (masked)
              sv = (k0 + f * 16 + g * 4 + r <= q0 + (2 * qp + qf) * 16 + lr) ? sv : -1e30f;
            p[r] = fast_exp2(sv);
          }
          lsum[2 * qp + qf] += (p[0] + p[1]) + (p[2] + p[3]);
          pk[qf][f][0] = pack2bf(p[0], p[1]);
          pk[qf][f][1] = pack2bf(p[2], p[3]);
        }

      // Redistribute C/D layout -> B-frag layout via shuffles (proven).
      const int sA = lr + 16 * (2 * (g & 1));
      const int sB = sA + 16;
#pragma unroll
      for (int qf = 0; qf < 2; ++qf)
#pragma unroll
        for (int kk = 0; kk < 2; ++kk) {
          int dw[4];
#pragma unroll
          for (int j2 = 0; j2 < 4; ++j2) {
            const int S = (j2 < 2) ? sA : sB;
            int v0 = __shfl((int)pk[qf][2 * kk][j2 & 1], S, 64);
            int v1 = __shfl((int)pk[qf][2 * kk + 1][j2 & 1], S, 64);
            dw[j2] = (g & 2) ? v1 : v0;
          }
          int4 dwi = make_int4(dw[0], dw[1], dw[2], dw[3]);
          bf16x8 pa = __builtin_bit_cast(bf16x8, dwi);
#pragma unroll
          for (int df = 0; df < 4; ++df)
            o[2 * qp + qf][df] = __builtin_amdgcn_mfma_f32_16x16x32_bf16(
                vf[df][kk], pa, o[2 * qp + qf][df], 0, 0, 0);
        }
    }
  };

  for (int t = w; t < last; t += 4) tile(t * 64, false);
  if (last >= 0 && (last & 3) == w) tile(last * 64, true);

  // l partial: reduce across the 4 g-groups (q = lr in every group)
#pragma unroll
  for (int qf4 = 0; qf4 < 4; ++qf4) {
    lsum[qf4] += __shfl_xor(lsum[qf4], 16);
    lsum[qf4] += __shfl_xor(lsum[qf4], 32);
  }

  // Write partials to LDS
#pragma unroll
  for (int qf4 = 0; qf4 < 4; ++qf4) {
    if (g == 0) Lp[w][qf4 * 16 + lr] = lsum[qf4];
#pragma unroll
    for (int df = 0; df < 4; ++df)
      *reinterpret_cast<f32x4*>(&Ol[w][qf4 * 16 + lr][df * 16 + g * 4]) = o[qf4][df];
  }
  __syncthreads();

  // Combine: thread handles query ql = tid>>2, d-range [(tid&3)*16, +16)
  const int ql = tid >> 2, d0 = (tid & 3) * 16;
  const float l = Lp[0][ql] + Lp[1][ql] + Lp[2][ql] + Lp[3][ql];
  const float rl = 1.0f / l;
  float sacc[16] = {};
#pragma unroll
  for (int w2 = 0; w2 < 4; ++w2)
#pragma unroll
    for (int c4 = 0; c4 < 4; ++c4) {
      f32x4 a = *reinterpret_cast<const f32x4*>(&Ol[w2][ql][d0 + c4 * 4]);
      sacc[c4 * 4 + 0] += a[0]; sacc[c4 * 4 + 1] += a[1];
      sacc[c4 * 4 + 2] += a[2]; sacc[c4 * 4 + 3] += a[3];
    }
  uint4 ov0, ov1;
  ov0.x = pack2bf(sacc[0] * rl,  sacc[1] * rl);
  ov0.y = pack2bf(sacc[2] * rl,  sacc[3] * rl);
  ov0.z = pack2bf(sacc[4] * rl,  sacc[5] * rl);
  ov0.w = pack2bf(sacc[6] * rl,  sacc[7] * rl);
  ov1.x = pack2bf(sacc[8] * rl,  sacc[9] * rl);
  ov1.y = pack2bf(sacc[10] * rl, sacc[11] * rl);
  ov1.z = pack2bf(sacc[12] * rl, sacc[13] * rl);
  ov1.w = pack2bf(sacc[14] * rl, sacc[15] * rl);
  unsigned short* yrow = &Yb[(size_t)(b * T_SEQ + q0 + ql) * DMODEL + h * DKH + d0];
  *reinterpret_cast<uint4*>(yrow) = ov0;
  *reinterpret_cast<uint4*>(yrow + 8) = ov1;
}

extern "C" void kernel_launch(void* const* d_in, const int* in_sizes, int n_in,
                              void* d_out, int out_size, void* d_ws, size_t ws_size,
                              hipStream_t stream) {
  const float* x  = (const float*)d_in[0];
  const float* wq = (const float*)d_in[1];
  const float* bq = (const float*)d_in[2];
  const float* wk = (const float*)d_in[3];
  const float* bk = (const float*)d_in[4];
  const float* wv = (const float*)d_in[5];
  const float* bv = (const float*)d_in[6];
  const float* wo = (const float*)d_in[7];
  const float* bo = (const float*)d_in[8];

  char* ws = (char*)d_ws;
  unsigned short* xb   = (unsigned short*)(ws + (size_t)0);          // [0,8) MB
  unsigned short* Wqkv = (unsigned short*)(ws + ((size_t)8  << 20)); // [8,14) MB
  unsigned short* Wob  = (unsigned short*)(ws + ((size_t)14 << 20)); // [14,16) MB
  unsigned short* Qb   = (unsigned short*)(ws + ((size_t)16 << 20)); // [16,24) MB
  unsigned short* Kb   = (unsigned short*)(ws + ((size_t)24 << 20)); // [24,32) MB
  unsigned short* Vtb  = (unsigned short*)(ws + ((size_t)32 << 20)); // [32,40) MB
  unsigned short* Yb   = (unsigned short*)(ws + ((size_t)40 << 20)); // [40,48) MB

  const int M = BATCH * T_SEQ;      // 4096
  const int N = DMODEL;             // 1024
  const int Kd = DMODEL;            // 1024
  const float qscale = 0.125f * 1.44269504f;  // 1/sqrt(dk) * log2(e)

  const int ncast = (M * DMODEL + 4 * DMODEL * DMODEL) / 4;  // elements/4
  castall<<<(ncast + 255) / 256, 256, 0, stream>>>(
      x, wq, wk, wv, wo, xb, Wqkv, Wob, qscale);

  gemm_qkv<<<dim3(3 * N / 128, M / 64), 256, 0, stream>>>(
      xb, Wqkv, bq, bk, bv, Qb, Kb, Vtb, Kd, qscale);

  attn_k<<<dim3((T_SEQ / 64) * BATCH * NHEAD), 256, 0, stream>>>(Qb, Kb, Vtb, Yb);

  gemm_out<<<dim3(N / 128, M / 64), 256, 0, stream>>>(Yb, Wob, bo, (float*)d_out, N, Kd);
}